// Round 14
// baseline (115.483 us; speedup 1.0000x reference)
//
#include <hip/hip_runtime.h>

namespace {

constexpr int T_LEN = 512;
constexpr float LOG2E = 1.4426950408889634f;

typedef _Float16 half4 __attribute__((ext_vector_type(4)));
typedef _Float16 half2v __attribute__((ext_vector_type(2)));
typedef float v4f __attribute__((ext_vector_type(4)));

__device__ __forceinline__ float fexp2(float a) {
#if __has_builtin(__builtin_amdgcn_exp2f)
    return __builtin_amdgcn_exp2f(a);
#else
    return exp2f(a);
#endif
}

__device__ __forceinline__ v4f mfma16h(half4 a, half4 b, v4f c) {
#if __has_builtin(__builtin_amdgcn_mfma_f32_16x16x16f16)
    return __builtin_amdgcn_mfma_f32_16x16x16f16(a, b, c, 0, 0, 0);
#else
    v4f d;
    asm volatile("v_mfma_f32_16x16x16_f16 %0, %1, %2, %3\n\ts_nop 7\n\ts_nop 7"
                 : "=v"(d) : "v"(a), "v"(b), "v"(c));
    return d;
#endif
}

__device__ __forceinline__ unsigned pk_f16(float a, float b) {
#if __has_builtin(__builtin_amdgcn_cvt_pkrtz)
    return __builtin_bit_cast(unsigned, __builtin_amdgcn_cvt_pkrtz(a, b));
#else
    half2v r; r[0] = (_Float16)a; r[1] = (_Float16)b;
    return __builtin_bit_cast(unsigned, r);
#endif
}

// DPP mov. row_ror:8 (0x128) == lane XOR 8 within 16-lane rows (self-inverse).
template<int CTRL>
__device__ __forceinline__ unsigned dpp_mov_u(unsigned v) {
    return (unsigned)__builtin_amdgcn_mov_dpp((int)v, CTRL, 0xF, 0xF, false);
}

// Pade [7/6] tanh, clamped to |y|<=5.2. Max abs err ~2e-4 (clamp 6e-5 + rational
// ~1.2e-4 at the edge; ~1e-6 mid-range). One rcp (trans-depth 1 vs exp2+rcp=2).
__device__ __forceinline__ float tanh_pade(float y) {
    float yc = fminf(fmaxf(y, -5.2f), 5.2f);
    float u  = yc * yc;
    float u2 = u * u;
    float nlo = __builtin_fmaf(u, 17325.0f, 135135.0f);
    float nhi = u + 378.0f;
    float N   = __builtin_fmaf(u2, nhi, nlo);
    float dlo = __builtin_fmaf(u, 62370.0f, 135135.0f);
    float dhi = __builtin_fmaf(u, 28.0f, 3150.0f);
    float D   = __builtin_fmaf(u2, dhi, dlo);
    return (yc * N) * __builtin_amdgcn_rcpf(D);
}

// one (row, elem) gate evaluation + h update.
// d_r = (xr+hr+br)/2 ; d_z = -log2e*(xz+hz+bz) ; d_n = hn (unscaled)
__device__ __forceinline__ float gru_pair(float d_r, float d_z, float d_n,
                                          float xt, float wihn, float bihn,
                                          float hp) {
    float r  = __builtin_fmaf(tanh_pade(d_r), 0.5f, 0.5f);   // sigmoid via tanh
    float Ez = fexp2(d_z);                                    // off critical path
    float z  = __builtin_amdgcn_rcpf(1.0f + Ez);
    float xn = __builtin_fmaf(xt, wihn, bihn);
    float yn = __builtin_fmaf(r, d_n, xn);
    float n  = tanh_pade(yn);
    return __builtin_fmaf(z, hp - n, n);                      // (1-z)*n + z*h
}

__global__ __launch_bounds__(64) void gru_pd(
        const float* __restrict__ x,
        const float* __restrict__ W_ih,
        const float* __restrict__ W_hh,
        const float* __restrict__ b_ih,
        const float* __restrict__ b_hh,
        const float* __restrict__ fc_w,
        const float* __restrict__ fc_b,
        float* __restrict__ out) {
    const int L  = threadIdx.x;      // 0..63
    const int e  = L & 15;           // MFMA column (cols e and e+8 duplicate)
    const int g  = L >> 4;           // row group; D rows jD..jD+3 of col e
    const int jD = g * 4;
    const int ehi  = (e >> 3) & 1;   // 0: gate rows jD,jD+1 ; 1: jD+2,jD+3
    const int ecol = e & 7;          // real batch column within the group
    const int be   = blockIdx.x * 8 + ecol;
    const int r0   = jD + 2 * ehi;   // first of the 2 gate rows this lane owns

    const float sR = 0.5f;           // r-gate: y_r = preact/2, r = .5+.5*T(y_r)
    const float sZ = -LOG2E;         // z-gate: exp2-based sigmoid
    // n-gate: unscaled (direct tanh via T)

    // ---- A fragments: W_hh rows (gate out m = e; k = jD..jD+3), f16
    half4 ar_h, az_h, an_h;
#pragma unroll
    for (int i = 0; i < 4; ++i) {
        ar_h[i] = (_Float16)(W_hh[(0  + e) * 16 + jD + i] * sR);
        az_h[i] = (_Float16)(W_hh[(16 + e) * 16 + jD + i] * sZ);
        an_h[i] = (_Float16)(W_hh[(32 + e) * 16 + jD + i]);
    }

    // ---- loop-invariant MFMA C-operands: bias vectors (xt folded post-sel)
    v4f c_r, c_z, c_n;
#pragma unroll
    for (int i = 0; i < 4; ++i) {
        int rj = jD + i;
        c_r[i] = (b_ih[rj]      + b_hh[rj])      * sR;
        c_z[i] = (b_ih[16 + rj] + b_hh[16 + rj]) * sZ;
        c_n[i] = b_hh[32 + rj];
    }
    // per-lane scalars for this lane's 2 gate rows
    const float wihr0 = W_ih[r0]          * sR, wihr1 = W_ih[r0 + 1]      * sR;
    const float wihz0 = W_ih[16 + r0]     * sZ, wihz1 = W_ih[16 + r0 + 1] * sZ;
    const float wihn0 = W_ih[32 + r0],          wihn1 = W_ih[32 + r0 + 1];
    const float bihn0 = b_ih[32 + r0],          bihn1 = b_ih[32 + r0 + 1];

    // ---- x timeline for this column (duplicate lanes hit identical addresses)
    const float4* xb = (const float4*)(x + (size_t)be * T_LEN);
    float4 xc0 = xb[0], xc1 = xb[1], xc2 = xb[2], xc3 = xb[3];

    float hp0 = 0.f, hp1 = 0.f;          // this lane's 2 h rows (fp32 master)
    uint2 hz; hz.x = 0u; hz.y = 0u;
    half4 hf = __builtin_bit_cast(half4, hz);   // B-frag: rows jD..jD+3 (f16)

#pragma unroll 1
    for (int c = 0; c < T_LEN / 16; ++c) {
        float4 xn0, xn1, xn2, xn3;
        if (c + 1 < T_LEN / 16) {
            xn0 = xb[(c + 1) * 4 + 0];
            xn1 = xb[(c + 1) * 4 + 1];
            xn2 = xb[(c + 1) * 4 + 2];
            xn3 = xb[(c + 1) * 4 + 3];
        }
#pragma unroll
        for (int s = 0; s < 16; ++s) {
            float4 q4 = (s < 4) ? xc0 : (s < 8) ? xc1 : (s < 12) ? xc2 : xc3;
            float xt  = ((s & 3) == 0) ? q4.x : ((s & 3) == 1) ? q4.y
                      : ((s & 3) == 2) ? q4.z : q4.w;

            // matvec on MFMA pipe: ONE f16 MFMA per gate, bias in C.
            // dr issued first: it heads the critical path (r -> n serialization).
            v4f dr = mfma16h(ar_h, hf, c_r);
            v4f dn = mfma16h(an_h, hf, c_n);
            v4f dz = mfma16h(az_h, hf, c_z);

            // column-duplication split: e<8 -> regs [0,1]; e>=8 -> [2,3]
            float d_r0 = __builtin_fmaf(xt, wihr0, ehi ? dr[2] : dr[0]);
            float d_r1 = __builtin_fmaf(xt, wihr1, ehi ? dr[3] : dr[1]);
            float d_z0 = __builtin_fmaf(xt, wihz0, ehi ? dz[2] : dz[0]);
            float d_z1 = __builtin_fmaf(xt, wihz1, ehi ? dz[3] : dz[1]);
            float d_n0 = ehi ? dn[2] : dn[0];
            float d_n1 = ehi ? dn[3] : dn[1];

            float h0n = gru_pair(d_r0, d_z0, d_n0, xt, wihn0, bihn0, hp0);
            float h1n = gru_pair(d_r1, d_z1, d_n1, xt, wihn1, bihn1, hp1);
            hp0 = h0n; hp1 = h1n;

            // reassemble B-frag: partner rowpair via DPP row_ror:8 (VALU)
            unsigned mine = pk_f16(h0n, h1n);
            unsigned oth  = dpp_mov_u<0x128>(mine);   // lane XOR 8 within 16-row
            uint2 hv;
            hv.x = ehi ? oth  : mine;    // rows jD, jD+1
            hv.y = ehi ? mine : oth;     // rows jD+2, jD+3
            hf = __builtin_bit_cast(half4, hv);
        }
        if (c + 1 < T_LEN / 16) { xc0 = xn0; xc1 = xn1; xc2 = xn2; xc3 = xn3; }
    }

    // ---- FC: coset {L^8, L^16, L^32} covers all 16 rows of col ecol once
    float p = hp0 * fc_w[r0] + hp1 * fc_w[r0 + 1];
    p += __shfl_xor(p, 8, 64);
    p += __shfl_xor(p, 16, 64);
    p += __shfl_xor(p, 32, 64);
    if (L < 8) out[blockIdx.x * 8 + L] = p + fc_b[0];
}

} // namespace

extern "C" void kernel_launch(void* const* d_in, const int* in_sizes, int n_in,
                              void* d_out, int out_size, void* d_ws, size_t ws_size,
                              hipStream_t stream) {
    const float* x    = (const float*)d_in[0];
    const float* W_ih = (const float*)d_in[1];
    const float* W_hh = (const float*)d_in[2];
    const float* b_ih = (const float*)d_in[3];
    const float* b_hh = (const float*)d_in[4];
    const float* fc_w = (const float*)d_in[5];
    const float* fc_b = (const float*)d_in[6];
    float* out = (float*)d_out;

    const int B = out_size;               // 8192
    const int blocks = B / 8;             // 8 elements per 1-wave block (2x col dup)
    gru_pd<<<blocks, 64, 0, stream>>>(x, W_ih, W_hh, b_ih, b_hh,
                                      fc_w, fc_b, out);
}

// Round 15
// 94.000 us; speedup vs baseline: 1.2286x; 1.2286x over previous
//
#include <hip/hip_runtime.h>

namespace {

constexpr int T_LEN = 512;
constexpr float LOG2E = 1.4426950408889634f;

typedef _Float16 half4 __attribute__((ext_vector_type(4)));
typedef _Float16 half2v __attribute__((ext_vector_type(2)));
typedef float v4f __attribute__((ext_vector_type(4)));

__device__ __forceinline__ float fexp2(float a) {
#if __has_builtin(__builtin_amdgcn_exp2f)
    return __builtin_amdgcn_exp2f(a);
#else
    return exp2f(a);
#endif
}

__device__ __forceinline__ v4f mfma16h(half4 a, half4 b, v4f c) {
#if __has_builtin(__builtin_amdgcn_mfma_f32_16x16x16f16)
    return __builtin_amdgcn_mfma_f32_16x16x16f16(a, b, c, 0, 0, 0);
#else
    v4f d;
    asm volatile("v_mfma_f32_16x16x16_f16 %0, %1, %2, %3\n\ts_nop 7\n\ts_nop 7"
                 : "=v"(d) : "v"(a), "v"(b), "v"(c));
    return d;
#endif
}

__device__ __forceinline__ unsigned pk_f16(float a, float b) {
#if __has_builtin(__builtin_amdgcn_cvt_pkrtz)
    return __builtin_bit_cast(unsigned, __builtin_amdgcn_cvt_pkrtz(a, b));
#else
    half2v r; r[0] = (_Float16)a; r[1] = (_Float16)b;
    return __builtin_bit_cast(unsigned, r);
#endif
}

// DPP mov. row_ror:8 (0x128) == lane XOR 8 within 16-lane rows (self-inverse).
template<int CTRL>
__device__ __forceinline__ unsigned dpp_mov_u(unsigned v) {
    return (unsigned)__builtin_amdgcn_mov_dpp((int)v, CTRL, 0xF, 0xF, false);
}

// Two-row gate evaluation with cross-row reciprocal pooling: 6 exp2 + 2 rcp
// (was 6 exp2 + 4 rcp). r-pair shares one rcp; {z0,z1,v0,v1} share one rcp
// via partial products. Pool magnitude <= ~1e15 for this data (|preact|<~6,
// tanh-arg scaled by 2log2e -> pv <= ~2^16): safe in f32.
__device__ __forceinline__ void gru_two(float d_r0, float d_r1,
                                        float d_z0, float d_z1,
                                        float d_n0, float d_n1,
                                        float xn0, float xn1,
                                        float& hp0, float& hp1) {
    // r = sigmoid: d_r = -log2e*pre ; r = 1/(1+exp2(d_r))
    float Er0 = fexp2(d_r0), Er1 = fexp2(d_r1);
    float pr0 = 1.0f + Er0, pr1 = 1.0f + Er1;
    float ipr = __builtin_amdgcn_rcpf(pr0 * pr1);
    float r0 = ipr * pr1, r1 = ipr * pr0;
    // z exp2s issue early; their rcp is pooled with v below (z used only at blend)
    float Ez0 = fexp2(d_z0), Ez1 = fexp2(d_z1);
    float pz0 = 1.0f + Ez0, pz1 = 1.0f + Ez1;
    float A = pz0 * pz1;
    // n pre-activations (depend on r): v = 2log2e*(xn + r*hn), all pre-scaled
    float v0 = __builtin_fmaf(r0, d_n0, xn0);
    float v1 = __builtin_fmaf(r1, d_n1, xn1);
    float Ev0 = fexp2(v0), Ev1 = fexp2(v1);
    float pv0 = 1.0f + Ev0, pv1 = 1.0f + Ev1;
    float B = pv0 * pv1;
    float ip = __builtin_amdgcn_rcpf(A * B);
    float iA = ip * B, iB = ip * A;          // 1/A, 1/B
    float z0 = iA * pz1, z1 = iA * pz0;      // sigmoid(z-pre)
    float f0 = iB * pv1, f1 = iB * pv0;      // 1/(1+exp2(v))
    float n0 = __builtin_fmaf(-2.0f, f0, 1.0f);   // tanh
    float n1 = __builtin_fmaf(-2.0f, f1, 1.0f);
    hp0 = __builtin_fmaf(z0, hp0 - n0, n0);  // (1-z)*n + z*h
    hp1 = __builtin_fmaf(z1, hp1 - n1, n1);
}

__global__ __launch_bounds__(64) void gru_mfma8p(
        const float* __restrict__ x,
        const float* __restrict__ W_ih,
        const float* __restrict__ W_hh,
        const float* __restrict__ b_ih,
        const float* __restrict__ b_hh,
        const float* __restrict__ fc_w,
        const float* __restrict__ fc_b,
        float* __restrict__ out) {
    const int L  = threadIdx.x;      // 0..63
    const int e  = L & 15;           // MFMA column (cols e and e+8 duplicate)
    const int g  = L >> 4;           // row group; D rows jD..jD+3 of col e
    const int jD = g * 4;
    const int ehi  = (e >> 3) & 1;   // 0: gate rows jD,jD+1 ; 1: jD+2,jD+3
    const int ecol = e & 7;          // real batch column within the group
    const int be   = blockIdx.x * 8 + ecol;
    const int r0   = jD + 2 * ehi;   // first of the 2 gate rows this lane owns

    const float sR = -LOG2E;         // sigmoid scaling folded into weights
    const float sN = 2.0f * LOG2E;   // tanh scaling

    // ---- A fragments: W_hh rows (gate out m = e; k = jD..jD+3), scaled, f16
    half4 ar_h, az_h, an_h;
#pragma unroll
    for (int i = 0; i < 4; ++i) {
        ar_h[i] = (_Float16)(W_hh[(0  + e) * 16 + jD + i] * sR);
        az_h[i] = (_Float16)(W_hh[(16 + e) * 16 + jD + i] * sR);
        an_h[i] = (_Float16)(W_hh[(32 + e) * 16 + jD + i] * sN);
    }

    // ---- loop-invariant MFMA C-operands: bias vectors (xt folded post-sel)
    v4f c_r, c_z, c_n;
#pragma unroll
    for (int i = 0; i < 4; ++i) {
        int rj = jD + i;
        c_r[i] = (b_ih[rj]      + b_hh[rj])      * sR;
        c_z[i] = (b_ih[16 + rj] + b_hh[16 + rj]) * sR;
        c_n[i] = b_hh[32 + rj] * sN;
    }
    // per-lane scalars for this lane's 2 gate rows
    const float wihr0 = W_ih[r0]          * sR, wihr1 = W_ih[r0 + 1]      * sR;
    const float wihz0 = W_ih[16 + r0]     * sR, wihz1 = W_ih[16 + r0 + 1] * sR;
    const float wihn0 = W_ih[32 + r0]     * sN, wihn1 = W_ih[32 + r0 + 1] * sN;
    const float bihn0 = b_ih[32 + r0]     * sN, bihn1 = b_ih[32 + r0 + 1] * sN;

    // ---- x timeline for this column (duplicate lanes hit identical addresses)
    const float4* xb = (const float4*)(x + (size_t)be * T_LEN);
    float4 xc0 = xb[0], xc1 = xb[1], xc2 = xb[2], xc3 = xb[3];

    float hp0 = 0.f, hp1 = 0.f;          // this lane's 2 h rows (fp32 master)
    uint2 hz; hz.x = 0u; hz.y = 0u;
    half4 hf = __builtin_bit_cast(half4, hz);   // B-frag: rows jD..jD+3 (f16)

#pragma unroll 1
    for (int c = 0; c < T_LEN / 16; ++c) {
        float4 xn0, xn1, xn2, xn3;
        if (c + 1 < T_LEN / 16) {
            xn0 = xb[(c + 1) * 4 + 0];
            xn1 = xb[(c + 1) * 4 + 1];
            xn2 = xb[(c + 1) * 4 + 2];
            xn3 = xb[(c + 1) * 4 + 3];
        }
#pragma unroll
        for (int s = 0; s < 16; ++s) {
            float4 q4 = (s < 4) ? xc0 : (s < 8) ? xc1 : (s < 12) ? xc2 : xc3;
            float xt  = ((s & 3) == 0) ? q4.x : ((s & 3) == 1) ? q4.y
                      : ((s & 3) == 2) ? q4.z : q4.w;

            // matvec on MFMA pipe: ONE f16 MFMA per gate, bias in C.
            // dr first (heads chain), dn second (needed at v), dz last (blend).
            v4f dr = mfma16h(ar_h, hf, c_r);
            v4f dn = mfma16h(an_h, hf, c_n);
            v4f dz = mfma16h(az_h, hf, c_z);

            // column-duplication split: e<8 -> regs [0,1]; e>=8 -> [2,3];
            // fold x-projection post-selection (1 FMA per gate-row)
            float d_r0 = __builtin_fmaf(xt, wihr0, ehi ? dr[2] : dr[0]);
            float d_r1 = __builtin_fmaf(xt, wihr1, ehi ? dr[3] : dr[1]);
            float d_z0 = __builtin_fmaf(xt, wihz0, ehi ? dz[2] : dz[0]);
            float d_z1 = __builtin_fmaf(xt, wihz1, ehi ? dz[3] : dz[1]);
            float d_n0 = ehi ? dn[2] : dn[0];
            float d_n1 = ehi ? dn[3] : dn[1];
            float xn0_ = __builtin_fmaf(xt, wihn0, bihn0);
            float xn1_ = __builtin_fmaf(xt, wihn1, bihn1);

            gru_two(d_r0, d_r1, d_z0, d_z1, d_n0, d_n1, xn0_, xn1_, hp0, hp1);

            // reassemble B-frag: partner rowpair via DPP row_ror:8 (VALU)
            unsigned mine = pk_f16(hp0, hp1);
            unsigned oth  = dpp_mov_u<0x128>(mine);   // lane XOR 8 within 16-row
            uint2 hv;
            hv.x = ehi ? oth  : mine;    // rows jD, jD+1
            hv.y = ehi ? mine : oth;     // rows jD+2, jD+3
            hf = __builtin_bit_cast(half4, hv);
        }
        if (c + 1 < T_LEN / 16) { xc0 = xn0; xc1 = xn1; xc2 = xn2; xc3 = xn3; }
    }

    // ---- FC: coset {L^8, L^16, L^32} covers all 16 rows of col ecol once
    float p = hp0 * fc_w[r0] + hp1 * fc_w[r0 + 1];
    p += __shfl_xor(p, 8, 64);
    p += __shfl_xor(p, 16, 64);
    p += __shfl_xor(p, 32, 64);
    if (L < 8) out[blockIdx.x * 8 + L] = p + fc_b[0];
}

} // namespace

extern "C" void kernel_launch(void* const* d_in, const int* in_sizes, int n_in,
                              void* d_out, int out_size, void* d_ws, size_t ws_size,
                              hipStream_t stream) {
    const float* x    = (const float*)d_in[0];
    const float* W_ih = (const float*)d_in[1];
    const float* W_hh = (const float*)d_in[2];
    const float* b_ih = (const float*)d_in[3];
    const float* b_hh = (const float*)d_in[4];
    const float* fc_w = (const float*)d_in[5];
    const float* fc_b = (const float*)d_in[6];
    float* out = (float*)d_out;

    const int B = out_size;               // 8192
    const int blocks = B / 8;             // 8 elements per 1-wave block (2x col dup)
    gru_mfma8p<<<blocks, 64, 0, stream>>>(x, W_ih, W_hh, b_ih, b_hh,
                                          fc_w, fc_b, out);
}

// Round 16
// 87.565 us; speedup vs baseline: 1.3188x; 1.0735x over previous
//
#include <hip/hip_runtime.h>

namespace {

constexpr int T_LEN = 512;
constexpr float LOG2E = 1.4426950408889634f;

typedef _Float16 half4 __attribute__((ext_vector_type(4)));
typedef _Float16 half2v __attribute__((ext_vector_type(2)));
typedef float v4f __attribute__((ext_vector_type(4)));

__device__ __forceinline__ float fexp2(float a) {
#if __has_builtin(__builtin_amdgcn_exp2f)
    return __builtin_amdgcn_exp2f(a);
#else
    return exp2f(a);
#endif
}

__device__ __forceinline__ v4f mfma16h(half4 a, half4 b, v4f c) {
#if __has_builtin(__builtin_amdgcn_mfma_f32_16x16x16f16)
    return __builtin_amdgcn_mfma_f32_16x16x16f16(a, b, c, 0, 0, 0);
#else
    v4f d;
    asm volatile("v_mfma_f32_16x16x16_f16 %0, %1, %2, %3\n\ts_nop 7\n\ts_nop 7"
                 : "=v"(d) : "v"(a), "v"(b), "v"(c));
    return d;
#endif
}

__device__ __forceinline__ unsigned pk_f16(float a, float b) {
#if __has_builtin(__builtin_amdgcn_cvt_pkrtz)
    return __builtin_bit_cast(unsigned, __builtin_amdgcn_cvt_pkrtz(a, b));
#else
    half2v r; r[0] = (_Float16)a; r[1] = (_Float16)b;
    return __builtin_bit_cast(unsigned, r);
#endif
}

// DPP mov. row_ror:8 (0x128) == lane XOR 8 within 16-lane rows (self-inverse).
template<int CTRL>
__device__ __forceinline__ unsigned dpp_mov_u(unsigned v) {
    return (unsigned)__builtin_amdgcn_mov_dpp((int)v, CTRL, 0xF, 0xF, false);
}

// one (row, element) gate evaluation + h update (identical math to R5/R7/R10/R11).
// Spine: Er -> pr -> pr*pz -> rcp -> r -> v -> Ev -> rcp -> n -> h.
// z is off the spine (shares the r rcp; used only at the final blend).
__device__ __forceinline__ float gru_pair(float drp, float dzp, float dnp,
                                          float xt, float wihn, float bihn,
                                          float hp) {
    float Er = fexp2(drp);
    float Ez = fexp2(dzp);
    float pr = 1.0f + Er;
    float pz = 1.0f + Ez;
    float ip = __builtin_amdgcn_rcpf(pr * pz);
    float r  = ip * pz;                  // sigmoid(r-pre)
    float z  = ip * pr;                  // sigmoid(z-pre)
    float xn = __builtin_fmaf(xt, wihn, bihn);
    float v  = __builtin_fmaf(r, dnp, xn);
    float n  = __builtin_fmaf(-2.0f, __builtin_amdgcn_rcpf(1.0f + fexp2(v)), 1.0f);
    return __builtin_fmaf(z, hp - n, n); // (1-z)*n + z*h
}

__global__ __launch_bounds__(64) void gru_mfma8d(
        const float* __restrict__ x,
        const float* __restrict__ W_ih,
        const float* __restrict__ W_hh,
        const float* __restrict__ b_ih,
        const float* __restrict__ b_hh,
        const float* __restrict__ fc_w,
        const float* __restrict__ fc_b,
        float* __restrict__ out) {
    const int L  = threadIdx.x;      // 0..63
    const int e  = L & 15;           // MFMA column (cols e and e+8 duplicate)
    const int g  = L >> 4;           // row group; D rows jD..jD+3 of col e
    const int jD = g * 4;
    const int ehi  = (e >> 3) & 1;   // 0: gate rows jD,jD+1 ; 1: jD+2,jD+3
    const int ecol = e & 7;          // real batch column within the group
    const int be   = blockIdx.x * 8 + ecol;
    const int r0   = jD + 2 * ehi;   // first of the 2 gate rows this lane owns

    const float sR = -LOG2E;         // sigmoid scaling folded into weights
    const float sN = 2.0f * LOG2E;   // tanh scaling

    // ---- A fragments: W_hh rows (gate out m = e; k = jD..jD+3), scaled,
    //      single f16 (RTN).  3 fragments, 3 MFMAs per step.
    half4 ar_h, az_h, an_h;
#pragma unroll
    for (int i = 0; i < 4; ++i) {
        ar_h[i] = (_Float16)(W_hh[(0  + e) * 16 + jD + i] * sR);
        az_h[i] = (_Float16)(W_hh[(16 + e) * 16 + jD + i] * sR);
        an_h[i] = (_Float16)(W_hh[(32 + e) * 16 + jD + i] * sN);
    }

    // ---- loop-invariant MFMA C-operands: pure bias vectors (xt folded post-sel)
    v4f c_r, c_z, c_n;
#pragma unroll
    for (int i = 0; i < 4; ++i) {
        int rj = jD + i;
        c_r[i] = (b_ih[rj]      + b_hh[rj])      * sR;
        c_z[i] = (b_ih[16 + rj] + b_hh[16 + rj]) * sR;
        c_n[i] = b_hh[32 + rj] * sN;
    }
    // per-lane scalars for this lane's 2 gate rows
    const float wihr0 = W_ih[r0]          * sR, wihr1 = W_ih[r0 + 1]      * sR;
    const float wihz0 = W_ih[16 + r0]     * sR, wihz1 = W_ih[16 + r0 + 1] * sR;
    const float wihn0 = W_ih[32 + r0]     * sN, wihn1 = W_ih[32 + r0 + 1] * sN;
    const float bihn0 = b_ih[32 + r0]     * sN, bihn1 = b_ih[32 + r0 + 1] * sN;

    // ---- x timeline for this column (duplicate lanes hit identical addresses)
    const float4* xb = (const float4*)(x + (size_t)be * T_LEN);
    float4 xc0 = xb[0], xc1 = xb[1], xc2 = xb[2], xc3 = xb[3];

    float hp0 = 0.f, hp1 = 0.f;          // this lane's 2 h rows (fp32 master)
    uint2 hz; hz.x = 0u; hz.y = 0u;
    half4 hf = __builtin_bit_cast(half4, hz);   // B-frag: rows jD..jD+3 (f16)

#pragma unroll 1
    for (int c = 0; c < T_LEN / 16; ++c) {
        float4 xn0, xn1, xn2, xn3;
        if (c + 1 < T_LEN / 16) {
            xn0 = xb[(c + 1) * 4 + 0];
            xn1 = xb[(c + 1) * 4 + 1];
            xn2 = xb[(c + 1) * 4 + 2];
            xn3 = xb[(c + 1) * 4 + 3];
        }
#pragma unroll
        for (int s = 0; s < 16; ++s) {
            float4 q4 = (s < 4) ? xc0 : (s < 8) ? xc1 : (s < 12) ? xc2 : xc3;
            float xt  = ((s & 3) == 0) ? q4.x : ((s & 3) == 1) ? q4.y
                      : ((s & 3) == 2) ? q4.z : q4.w;

            // matvec on MFMA pipe: ONE f16 MFMA per gate, bias in C
            v4f dr = mfma16h(ar_h, hf, c_r);
            v4f dz = mfma16h(az_h, hf, c_z);
            v4f dn = mfma16h(an_h, hf, c_n);

            // column-duplication split: e<8 -> regs [0,1]; e>=8 -> [2,3];
            // fold x-projection in post-selection (1 FMA per gate-row)
            float d_r0 = __builtin_fmaf(xt, wihr0, ehi ? dr[2] : dr[0]);
            float d_r1 = __builtin_fmaf(xt, wihr1, ehi ? dr[3] : dr[1]);
            float d_z0 = __builtin_fmaf(xt, wihz0, ehi ? dz[2] : dz[0]);
            float d_z1 = __builtin_fmaf(xt, wihz1, ehi ? dz[3] : dz[1]);
            float d_n0 = ehi ? dn[2] : dn[0];
            float d_n1 = ehi ? dn[3] : dn[1];

            float h0n = gru_pair(d_r0, d_z0, d_n0, xt, wihn0, bihn0, hp0);
            float h1n = gru_pair(d_r1, d_z1, d_n1, xt, wihn1, bihn1, hp1);
            hp0 = h0n; hp1 = h1n;

            // reassemble B-frag: partner rowpair via DPP row_ror:8 (VALU, ~4 cyc,
            // replaces the ~110-cyc ds_swizzle on the recurrence critical path)
            unsigned mine = pk_f16(h0n, h1n);
            unsigned oth  = dpp_mov_u<0x128>(mine);   // lane XOR 8 within 16-row
            uint2 hv;
            hv.x = ehi ? oth  : mine;    // rows jD, jD+1
            hv.y = ehi ? mine : oth;     // rows jD+2, jD+3
            hf = __builtin_bit_cast(half4, hv);
        }
        if (c + 1 < T_LEN / 16) { xc0 = xn0; xc1 = xn1; xc2 = xn2; xc3 = xn3; }
    }

    // ---- FC: coset {L^8, L^16, L^32} covers all 16 rows of col ecol once
    float p = hp0 * fc_w[r0] + hp1 * fc_w[r0 + 1];
    p += __shfl_xor(p, 8, 64);
    p += __shfl_xor(p, 16, 64);
    p += __shfl_xor(p, 32, 64);
    if (L < 8) out[blockIdx.x * 8 + L] = p + fc_b[0];
}

} // namespace

extern "C" void kernel_launch(void* const* d_in, const int* in_sizes, int n_in,
                              void* d_out, int out_size, void* d_ws, size_t ws_size,
                              hipStream_t stream) {
    const float* x    = (const float*)d_in[0];
    const float* W_ih = (const float*)d_in[1];
    const float* W_hh = (const float*)d_in[2];
    const float* b_ih = (const float*)d_in[3];
    const float* b_hh = (const float*)d_in[4];
    const float* fc_w = (const float*)d_in[5];
    const float* fc_b = (const float*)d_in[6];
    float* out = (float*)d_out;

    const int B = out_size;               // 8192
    const int blocks = B / 8;             // 8 elements per 1-wave block (2x col dup)
    gru_mfma8d<<<blocks, 64, 0, stream>>>(x, W_ih, W_hh, b_ih, b_hh,
                                          fc_w, fc_b, out);
}